// Round 1
// baseline (873.568 us; speedup 1.0000x reference)
//
#include <hip/hip_runtime.h>
#include <math.h>

#define B 128
#define T 2048
#define H 200
#define G4 800   // 4*H
#define TT 64    // t-tile per block in scores kernel
#define TCH 256  // t-chunk per block in context kernel

// ---------------- prep kernels ----------------

__global__ __launch_bounds__(256) void prep_uat(const float* __restrict__ Ua,
                                                float* __restrict__ UaT) {
    int k = blockIdx.x;      // 0..H-1
    int h = threadIdx.x;     // 0..255 (padded)
    UaT[k * 256 + h] = (h < H) ? Ua[h * H + k] : 0.f;
}

__global__ __launch_bounds__(256) void prep_qb(const float* __restrict__ h0,
                                               const float* __restrict__ Wa,
                                               const float* __restrict__ ba,
                                               const float* __restrict__ bua,
                                               float* __restrict__ qb) {
    int b = blockIdx.x;
    int h = threadIdx.x;
    __shared__ float q[H];
    if (h < H) q[h] = h0[b * H + h];
    __syncthreads();
    if (h < H) {
        float a = ba[h] + bua[h];
        const float* w = Wa + h * H;
        #pragma unroll 4
        for (int k = 0; k < H; k++) a = fmaf(q[k], w[k], a);
        qb[b * H + h] = a;
    }
}

__global__ __launch_bounds__(256) void prep_hpre(const float* __restrict__ h0,
                                                 const float* __restrict__ W_hh,
                                                 const float* __restrict__ b_hh,
                                                 float* __restrict__ hpre) {
    int b = blockIdx.x;
    __shared__ float q[H];
    if (threadIdx.x < H) q[threadIdx.x] = h0[b * H + threadIdx.x];
    __syncthreads();
    for (int j = threadIdx.x; j < G4; j += 256) {
        float a = b_hh[j];
        const float* w = W_hh + j * H;
        #pragma unroll 4
        for (int k = 0; k < H; k++) a = fmaf(q[k], w[k], a);
        hpre[b * G4 + j] = a;
    }
}

// ---------------- scores: s[b,t] = Va . tanh(qb[b,:] + Ua@enc[b,t,:]) + bva ----------------
// Block: 256 threads = 4 waves. Wave w owns h in [50w, 50w+50); lane owns t = t0+lane.
// enc tile transposed in LDS [k][t]; UaT gives wave-uniform (scalar) Ua loads.

__global__ __launch_bounds__(256) void scores_kernel(const float* __restrict__ enc,
                                                     const float* __restrict__ UaT,
                                                     const float* __restrict__ qb,
                                                     const float* __restrict__ Va,
                                                     const float* __restrict__ bva,
                                                     float* __restrict__ scores) {
    __shared__ float elds[H * TT];        // 51200 B, [k][t]
    __shared__ float part[4][TT];

    int b    = blockIdx.y;
    int t0   = blockIdx.x * TT;
    int tid  = threadIdx.x;
    int lane = tid & 63;
    int w    = __builtin_amdgcn_readfirstlane(tid >> 6);  // force wave-uniform

    // stage: 64 rows x 200 floats, float4 loads, transpose into LDS
    const float4* src = (const float4*)(enc + (size_t)(b * T + t0) * H);
    for (int i = tid; i < TT * 50; i += 256) {
        int r = i / 50, c = i - r * 50;
        float4 v = src[r * 50 + c];
        elds[(4 * c + 0) * TT + r] = v.x;
        elds[(4 * c + 1) * TT + r] = v.y;
        elds[(4 * c + 2) * TT + r] = v.z;
        elds[(4 * c + 3) * TT + r] = v.w;
    }
    __syncthreads();

    float acc[50];
    #pragma unroll
    for (int j = 0; j < 50; j++) acc[j] = 0.f;

    const float* ua = UaT + w * 50;   // wave-uniform base
    for (int k = 0; k < H; k++) {
        float ev = elds[k * TT + lane];
        const float* uar = ua + k * 256;
        #pragma unroll
        for (int j = 0; j < 50; j++) acc[j] = fmaf(uar[j], ev, acc[j]);
    }

    const float* qbr = qb + b * H + w * 50;
    const float* var = Va + w * 50;
    float p = 0.f;
    #pragma unroll
    for (int j = 0; j < 50; j++) p += var[j] * tanhf(qbr[j] + acc[j]);
    part[w][lane] = p;
    __syncthreads();
    if (tid < TT) {
        float s = part[0][tid] + part[1][tid] + part[2][tid] + part[3][tid] + bva[0];
        scores[b * T + t0 + tid] = s;
    }
}

// ---------------- softmax over T per batch row ----------------

__global__ __launch_bounds__(256) void softmax_kernel(const float* __restrict__ scores,
                                                      float* __restrict__ attn) {
    int b = blockIdx.x, tid = threadIdx.x;
    __shared__ float red[256];
    float m = -1e30f;
    for (int i = tid; i < T; i += 256) m = fmaxf(m, scores[b * T + i]);
    red[tid] = m;
    __syncthreads();
    for (int s = 128; s > 0; s >>= 1) {
        if (tid < s) red[tid] = fmaxf(red[tid], red[tid + s]);
        __syncthreads();
    }
    m = red[0];
    __syncthreads();
    float l = 0.f;
    for (int i = tid; i < T; i += 256) l += expf(scores[b * T + i] - m);
    red[tid] = l;
    __syncthreads();
    for (int s = 128; s > 0; s >>= 1) {
        if (tid < s) red[tid] += red[tid + s];
        __syncthreads();
    }
    float inv = 1.f / red[0];
    for (int i = tid; i < T; i += 256) attn[b * T + i] = expf(scores[b * T + i] - m) * inv;
}

// ---------------- context[b,h] = sum_t attn[b,t] * enc[b,t,h] ----------------

__global__ __launch_bounds__(256) void context_kernel(const float* __restrict__ enc,
                                                      const float* __restrict__ attn,
                                                      float* __restrict__ ctx) {
    int b  = blockIdx.y;
    int t0 = blockIdx.x * TCH;
    int h  = threadIdx.x;
    if (h >= H) return;
    float a = 0.f;
    const float* e  = enc + (size_t)(b * T + t0) * H + h;
    const float* at = attn + b * T + t0;
    #pragma unroll 4
    for (int t = 0; t < TCH; t++) a = fmaf(at[t], e[(size_t)t * H], a);
    atomicAdd(&ctx[b * H + h], a);
}

// ---------------- decoder: 5 steps, one block per batch ----------------

__device__ __forceinline__ float sigm(float x) { return 1.f / (1.f + expf(-x)); }

__global__ __launch_bounds__(256) void decoder_kernel(const float* __restrict__ x,
                                                      const float* __restrict__ c0,
                                                      const float* __restrict__ ctx,
                                                      const float* __restrict__ hpre,
                                                      const float* __restrict__ W_ih,
                                                      const float* __restrict__ b_ih,
                                                      const float* __restrict__ W1,
                                                      const float* __restrict__ b1,
                                                      const float* __restrict__ W2,
                                                      const float* __restrict__ b2,
                                                      const float* __restrict__ W3,
                                                      const float* __restrict__ b3,
                                                      float* __restrict__ out) {
    int b = blockIdx.x, tid = threadIdx.x;
    __shared__ float s_ctx[H];
    __shared__ float s_gc[G4];
    __shared__ float s_wx[G4];
    __shared__ float s_out[H];
    __shared__ float s_o1[100];
    __shared__ float s_o2[50];
    __shared__ float s_x;

    if (tid < H) s_ctx[tid] = ctx[b * H + tid];
    if (tid == 0) s_x = x[b];
    __syncthreads();

    // g_const[j] = b_ih[j] + hpre[b,j] + ctx . W_ih[j,1:]
    for (int j = tid; j < G4; j += 256) {
        const float* wrow = W_ih + (size_t)j * (H + 1);
        float a = b_ih[j] + hpre[b * G4 + j];
        #pragma unroll 4
        for (int k = 0; k < H; k++) a = fmaf(wrow[1 + k], s_ctx[k], a);
        s_gc[j] = a;
        s_wx[j] = wrow[0];
    }
    __syncthreads();

    for (int s = 0; s < 5; s++) {
        float xv = s_x;
        __syncthreads();
        if (tid < H) {
            float ig = s_gc[tid]       + xv * s_wx[tid];
            float fg = s_gc[H + tid]   + xv * s_wx[H + tid];
            float gg = s_gc[2*H + tid] + xv * s_wx[2*H + tid];
            float og = s_gc[3*H + tid] + xv * s_wx[3*H + tid];
            float c  = sigm(fg) * c0[b * H + tid] + sigm(ig) * tanhf(gg);
            float hn = sigm(og) * tanhf(c);
            s_out[tid] = fmaxf(hn, 0.f);
        }
        __syncthreads();
        if (tid < 100) {
            float a = b1[tid];
            #pragma unroll 4
            for (int k = 0; k < H; k++) a = fmaf(W1[tid * H + k], s_out[k], a);
            s_o1[tid] = fmaxf(a, 0.f);
        }
        __syncthreads();
        if (tid < 50) {
            float a = b2[tid];
            #pragma unroll 4
            for (int k = 0; k < 100; k++) a = fmaf(W2[tid * 100 + k], s_o1[k], a);
            s_o2[tid] = fmaxf(a, 0.f);
        }
        __syncthreads();
        if (tid == 0) {
            float a = b3[0];
            for (int k = 0; k < 50; k++) a = fmaf(W3[k], s_o2[k], a);
            out[b * 5 + s] = a;
            s_x = a;   // feed back as next input
        }
        __syncthreads();
    }
}

// ---------------- launch ----------------

extern "C" void kernel_launch(void* const* d_in, const int* in_sizes, int n_in,
                              void* d_out, int out_size, void* d_ws, size_t ws_size,
                              hipStream_t stream) {
    const float* x    = (const float*)d_in[0];
    const float* h0   = (const float*)d_in[1];
    const float* c0   = (const float*)d_in[2];
    const float* enc  = (const float*)d_in[3];
    const float* Wa   = (const float*)d_in[4];
    const float* ba   = (const float*)d_in[5];
    const float* Ua   = (const float*)d_in[6];
    const float* bua  = (const float*)d_in[7];
    const float* Va   = (const float*)d_in[8];
    const float* bva  = (const float*)d_in[9];
    const float* W_ih = (const float*)d_in[10];
    const float* W_hh = (const float*)d_in[11];
    const float* b_ih = (const float*)d_in[12];
    const float* b_hh = (const float*)d_in[13];
    const float* W1   = (const float*)d_in[14];
    const float* b1   = (const float*)d_in[15];
    const float* W2   = (const float*)d_in[16];
    const float* b2   = (const float*)d_in[17];
    const float* W3   = (const float*)d_in[18];
    const float* b3   = (const float*)d_in[19];
    float* out = (float*)d_out;

    char* ws = (char*)d_ws;
    float* UaT    = (float*)(ws);                  // 200*256*4 = 204800
    float* qb     = (float*)(ws + 204800);         // 128*200*4 = 102400
    float* hpre   = (float*)(ws + 307200);         // 128*800*4 = 409600
    float* scores = (float*)(ws + 716800);         // 128*2048*4 = 1048576
    float* attn   = (float*)(ws + 1765376);        // 1048576
    float* ctx    = (float*)(ws + 2813952);        // 102400  (total ~2.9 MB)

    hipMemsetAsync(ctx, 0, B * H * sizeof(float), stream);
    prep_uat<<<dim3(H), 256, 0, stream>>>(Ua, UaT);
    prep_qb<<<dim3(B), 256, 0, stream>>>(h0, Wa, ba, bua, qb);
    prep_hpre<<<dim3(B), 256, 0, stream>>>(h0, W_hh, b_hh, hpre);
    scores_kernel<<<dim3(T / TT, B), 256, 0, stream>>>(enc, UaT, qb, Va, bva, scores);
    softmax_kernel<<<dim3(B), 256, 0, stream>>>(scores, attn);
    context_kernel<<<dim3(T / TCH, B), 256, 0, stream>>>(enc, attn, ctx);
    decoder_kernel<<<dim3(B), 256, 0, stream>>>(x, c0, ctx, hpre, W_ih, b_ih,
                                                W1, b1, W2, b2, W3, b3, out);
}

// Round 2
// 651.713 us; speedup vs baseline: 1.3404x; 1.3404x over previous
//
#include <hip/hip_runtime.h>
#include <math.h>

#define B 128
#define T 2048
#define H 200
#define G4 800   // 4*H
#define KP 224   // K padded to multiple of 32
#define MP 256   // M (h_out) padded to 16 tiles of 16
#define LROW 224 // LDS row stride (bf16 units) for enc tile

typedef short short8 __attribute__((ext_vector_type(8)));
typedef float floatx4 __attribute__((ext_vector_type(4)));

__device__ __forceinline__ unsigned short f2bf(float x) {
    unsigned u = __float_as_uint(x);
    return (unsigned short)((u + 0x7fffu + ((u >> 16) & 1u)) >> 16);
}

// ---------------- prep: Ua fp32 [200][200] -> bf16 padded [256][224] ----------------
__global__ __launch_bounds__(256) void prep_uab(const float* __restrict__ Ua,
                                                unsigned short* __restrict__ Uab) {
    int row = blockIdx.x;   // 0..255
    int col = threadIdx.x;  // 0..255
    if (col < KP) {
        float v = (row < H && col < H) ? Ua[row * H + col] : 0.f;
        Uab[row * KP + col] = f2bf(v);
    }
}

__global__ __launch_bounds__(256) void prep_qb(const float* __restrict__ h0,
                                               const float* __restrict__ Wa,
                                               const float* __restrict__ ba,
                                               const float* __restrict__ bua,
                                               float* __restrict__ qb) {
    int b = blockIdx.x;
    int h = threadIdx.x;
    __shared__ float qs[H];
    if (h < H) qs[h] = h0[b * H + h];
    __syncthreads();
    if (h < H) {
        float a = ba[h] + bua[h];
        const float* w = Wa + h * H;
        #pragma unroll 4
        for (int k = 0; k < H; k++) a = fmaf(qs[k], w[k], a);
        qb[b * H + h] = a;
    }
}

__global__ __launch_bounds__(256) void prep_hpre(const float* __restrict__ h0,
                                                 const float* __restrict__ W_hh,
                                                 const float* __restrict__ b_hh,
                                                 float* __restrict__ hpre) {
    int b = blockIdx.x;
    __shared__ float qs[H];
    if (threadIdx.x < H) qs[threadIdx.x] = h0[b * H + threadIdx.x];
    __syncthreads();
    for (int j = threadIdx.x; j < G4; j += 256) {
        float a = b_hh[j];
        const float* w = W_hh + j * H;
        #pragma unroll 4
        for (int k = 0; k < H; k++) a = fmaf(qs[k], w[k], a);
        hpre[b * G4 + j] = a;
    }
}

// ---------------- scores via MFMA ----------------
// Grid: 512 blocks = (b, quarter). Block handles 512 t in 8 chunks of 64.
// Wave w owns m-tiles w*4..w*4+3 (h_out 64w..64w+63), A-frags register-resident.
// enc chunk staged in LDS as bf16 [64 t][224 k], row stride 448B (bank-uniform for b128).
__global__ __launch_bounds__(256, 2) void scores_mfma(const float* __restrict__ enc,
                                                      const unsigned short* __restrict__ Uab,
                                                      const float* __restrict__ qb,
                                                      const float* __restrict__ Va,
                                                      const float* __restrict__ bva,
                                                      float* __restrict__ scores) {
    __shared__ unsigned short elds[64 * LROW];   // 28672 B
    __shared__ float part[4][64];
    __shared__ float s_qb[MP];
    __shared__ float s_va[MP];

    int blk   = blockIdx.x;
    int b     = blk >> 2;
    int tbase = (blk & 3) * 512;
    int tid   = threadIdx.x;
    int lane  = tid & 63;
    int w     = tid >> 6;
    int r     = lane & 15;
    int q     = lane >> 4;

    // zero elds once (establishes k-pad cols 200..223 = 0 forever)
    for (int i = tid; i < 64 * LROW / 2; i += 256) ((unsigned*)elds)[i] = 0u;
    if (tid < MP) {
        s_qb[tid] = (tid < H) ? qb[b * H + tid] : 0.f;
        s_va[tid] = (tid < H) ? Va[tid] : 0.f;
    }

    // A fragments: af[mi][ks] = Uab[(w*4+mi)*16 + r][ks*32 + q*8 .. +7]
    short8 af[4][7];
    #pragma unroll
    for (int mi = 0; mi < 4; mi++)
        #pragma unroll
        for (int ks = 0; ks < 7; ks++) {
            const unsigned short* p = Uab + ((w * 4 + mi) * 16 + r) * KP + ks * 32 + q * 8;
            af[mi][ks] = *(const short8*)p;
        }
    float bv = bva[0];
    __syncthreads();   // elds zeroing complete before staging overwrites

    for (int ch = 0; ch < 8; ch++) {
        int t0 = tbase + ch * 64;
        // stage enc[b, t0..t0+63, :] -> bf16 LDS
        const float4* src = (const float4*)(enc + (size_t)(b * T + t0) * H);
        for (int i = tid; i < 64 * 50; i += 256) {
            int rr = i / 50, cc = i - rr * 50;
            float4 v = src[rr * 50 + cc];
            unsigned lo = (unsigned)f2bf(v.x) | ((unsigned)f2bf(v.y) << 16);
            unsigned hi = (unsigned)f2bf(v.z) | ((unsigned)f2bf(v.w) << 16);
            unsigned* dst = (unsigned*)(elds + rr * LROW + cc * 4);
            dst[0] = lo;
            dst[1] = hi;
        }
        __syncthreads();

        #pragma unroll
        for (int nt = 0; nt < 4; nt++) {
            floatx4 Cm[4];
            #pragma unroll
            for (int mi = 0; mi < 4; mi++) Cm[mi] = (floatx4){0.f, 0.f, 0.f, 0.f};
            #pragma unroll
            for (int ks = 0; ks < 7; ks++) {
                short8 bf = *(const short8*)(elds + (nt * 16 + r) * LROW + ks * 32 + q * 8);
                #pragma unroll
                for (int mi = 0; mi < 4; mi++)
                    Cm[mi] = __builtin_amdgcn_mfma_f32_16x16x32_bf16(af[mi][ks], bf, Cm[mi], 0, 0, 0);
            }
            // epilogue: p = sum over this wave's 16 h-rows of Va[h]*tanh(qb[h]+kproj)
            float p = 0.f;
            #pragma unroll
            for (int mi = 0; mi < 4; mi++)
                #pragma unroll
                for (int rg = 0; rg < 4; rg++) {
                    int h = (w * 4 + mi) * 16 + q * 4 + rg;
                    p += s_va[h] * tanhf(s_qb[h] + Cm[mi][rg]);
                }
            p += __shfl_xor(p, 16);
            p += __shfl_xor(p, 32);
            if (q == 0) part[w][nt * 16 + r] = p;
        }
        __syncthreads();
        if (tid < 64) {
            float s = part[0][tid] + part[1][tid] + part[2][tid] + part[3][tid] + bv;
            scores[b * T + t0 + tid] = s;
        }
        __syncthreads();
    }
}

// ---------------- softmax stats (m, 1/l) per batch row ----------------
__global__ __launch_bounds__(256) void softmax_stats(const float* __restrict__ scores,
                                                     float* __restrict__ stats) {
    int b = blockIdx.x, tid = threadIdx.x;
    __shared__ float red[256];
    float m = -1e30f;
    for (int i = tid; i < T; i += 256) m = fmaxf(m, scores[b * T + i]);
    red[tid] = m;
    __syncthreads();
    for (int s = 128; s > 0; s >>= 1) {
        if (tid < s) red[tid] = fmaxf(red[tid], red[tid + s]);
        __syncthreads();
    }
    m = red[0];
    __syncthreads();
    float l = 0.f;
    for (int i = tid; i < T; i += 256) l += expf(scores[b * T + i] - m);
    red[tid] = l;
    __syncthreads();
    for (int s = 128; s > 0; s >>= 1) {
        if (tid < s) red[tid] += red[tid + s];
        __syncthreads();
    }
    if (tid == 0) {
        stats[b * 2]     = m;
        stats[b * 2 + 1] = 1.f / red[0];
    }
}

// ---------------- context[b,h] = sum_t softmax(scores)[b,t] * enc[b,t,h] ----------------
__global__ __launch_bounds__(256) void context_kernel(const float* __restrict__ enc,
                                                      const float* __restrict__ scores,
                                                      const float* __restrict__ stats,
                                                      float* __restrict__ ctx) {
    int b  = blockIdx.y;
    int t0 = blockIdx.x * 256;
    int tid = threadIdx.x;
    __shared__ float s_w[256];
    float m = stats[b * 2], invl = stats[b * 2 + 1];
    s_w[tid] = expf(scores[b * T + t0 + tid] - m) * invl;
    __syncthreads();
    if (tid < H) {
        float a = 0.f;
        const float* e = enc + (size_t)(b * T + t0) * H + tid;
        #pragma unroll 4
        for (int t = 0; t < 256; t++) a = fmaf(s_w[t], e[(size_t)t * H], a);
        atomicAdd(&ctx[b * H + tid], a);
    }
}

// ---------------- decoder: 5 steps, one block per batch ----------------
__device__ __forceinline__ float sigm(float x) { return 1.f / (1.f + expf(-x)); }

__global__ __launch_bounds__(256) void decoder_kernel(const float* __restrict__ x,
                                                      const float* __restrict__ c0,
                                                      const float* __restrict__ ctx,
                                                      const float* __restrict__ hpre,
                                                      const float* __restrict__ W_ih,
                                                      const float* __restrict__ b_ih,
                                                      const float* __restrict__ W1,
                                                      const float* __restrict__ b1,
                                                      const float* __restrict__ W2,
                                                      const float* __restrict__ b2,
                                                      const float* __restrict__ W3,
                                                      const float* __restrict__ b3,
                                                      float* __restrict__ out) {
    int b = blockIdx.x, tid = threadIdx.x;
    __shared__ float s_ctx[H];
    __shared__ float s_gc[G4];
    __shared__ float s_wx[G4];
    __shared__ float s_out[H];
    __shared__ float s_o1[100];
    __shared__ float s_o2[50];
    __shared__ float s_x;

    if (tid < H) s_ctx[tid] = ctx[b * H + tid];
    if (tid == 0) s_x = x[b];
    __syncthreads();

    for (int j = tid; j < G4; j += 256) {
        const float* wrow = W_ih + (size_t)j * (H + 1);
        float a = b_ih[j] + hpre[b * G4 + j];
        #pragma unroll 4
        for (int k = 0; k < H; k++) a = fmaf(wrow[1 + k], s_ctx[k], a);
        s_gc[j] = a;
        s_wx[j] = wrow[0];
    }
    __syncthreads();

    for (int s = 0; s < 5; s++) {
        float xv = s_x;
        __syncthreads();
        if (tid < H) {
            float ig = s_gc[tid]         + xv * s_wx[tid];
            float fg = s_gc[H + tid]     + xv * s_wx[H + tid];
            float gg = s_gc[2 * H + tid] + xv * s_wx[2 * H + tid];
            float og = s_gc[3 * H + tid] + xv * s_wx[3 * H + tid];
            float c  = sigm(fg) * c0[b * H + tid] + sigm(ig) * tanhf(gg);
            float hn = sigm(og) * tanhf(c);
            s_out[tid] = fmaxf(hn, 0.f);
        }
        __syncthreads();
        if (tid < 100) {
            float a = b1[tid];
            #pragma unroll 4
            for (int k = 0; k < H; k++) a = fmaf(W1[tid * H + k], s_out[k], a);
            s_o1[tid] = fmaxf(a, 0.f);
        }
        __syncthreads();
        if (tid < 50) {
            float a = b2[tid];
            #pragma unroll 4
            for (int k = 0; k < 100; k++) a = fmaf(W2[tid * 100 + k], s_o1[k], a);
            s_o2[tid] = fmaxf(a, 0.f);
        }
        __syncthreads();
        if (tid == 0) {
            float a = b3[0];
            for (int k = 0; k < 50; k++) a = fmaf(W3[k], s_o2[k], a);
            out[b * 5 + s] = a;
            s_x = a;
        }
        __syncthreads();
    }
}

// ---------------- launch ----------------
extern "C" void kernel_launch(void* const* d_in, const int* in_sizes, int n_in,
                              void* d_out, int out_size, void* d_ws, size_t ws_size,
                              hipStream_t stream) {
    (void)in_sizes; (void)n_in; (void)out_size; (void)ws_size;
    const float* x    = (const float*)d_in[0];
    const float* h0   = (const float*)d_in[1];
    const float* c0   = (const float*)d_in[2];
    const float* enc  = (const float*)d_in[3];
    const float* Wa   = (const float*)d_in[4];
    const float* ba   = (const float*)d_in[5];
    const float* Ua   = (const float*)d_in[6];
    const float* bua  = (const float*)d_in[7];
    const float* Va   = (const float*)d_in[8];
    const float* bva  = (const float*)d_in[9];
    const float* W_ih = (const float*)d_in[10];
    const float* W_hh = (const float*)d_in[11];
    const float* b_ih = (const float*)d_in[12];
    const float* b_hh = (const float*)d_in[13];
    const float* W1   = (const float*)d_in[14];
    const float* b1   = (const float*)d_in[15];
    const float* W2   = (const float*)d_in[16];
    const float* b2   = (const float*)d_in[17];
    const float* W3   = (const float*)d_in[18];
    const float* b3   = (const float*)d_in[19];
    float* out = (float*)d_out;

    char* ws = (char*)d_ws;
    unsigned short* Uab = (unsigned short*)(ws);        // 256*224*2 = 114688
    float* qb     = (float*)(ws + 114688);              // 102400
    float* hpre   = (float*)(ws + 217088);              // 409600
    float* scores = (float*)(ws + 626688);              // 1048576
    float* stats  = (float*)(ws + 1675264);             // 1024
    float* ctx    = (float*)(ws + 1676288);             // 102400 (total ~1.78 MB)

    hipMemsetAsync(ctx, 0, B * H * sizeof(float), stream);
    prep_uab<<<dim3(256), 256, 0, stream>>>(Ua, Uab);
    prep_qb<<<dim3(B), 256, 0, stream>>>(h0, Wa, ba, bua, qb);
    prep_hpre<<<dim3(B), 256, 0, stream>>>(h0, W_hh, b_hh, hpre);
    scores_mfma<<<dim3(512), 256, 0, stream>>>(enc, Uab, qb, Va, bva, scores);
    softmax_stats<<<dim3(B), 256, 0, stream>>>(scores, stats);
    context_kernel<<<dim3(T / 256, B), 256, 0, stream>>>(enc, scores, stats, ctx);
    decoder_kernel<<<dim3(B), 256, 0, stream>>>(x, c0, ctx, hpre, W_ih, b_ih,
                                                W1, b1, W2, b2, W3, b3, out);
}

// Round 3
// 605.026 us; speedup vs baseline: 1.4439x; 1.0772x over previous
//
#include <hip/hip_runtime.h>
#include <math.h>

#define B 128
#define T 2048
#define H 200
#define G4 800   // 4*H
#define KP 224   // K padded to multiple of 32
#define MP 256   // M (h_out) padded to 16 tiles of 16
#define LROW 224 // LDS row stride (bf16 units) for enc tile

typedef short short8 __attribute__((ext_vector_type(8)));
typedef float floatx4 __attribute__((ext_vector_type(4)));

__device__ __forceinline__ unsigned short f2bf(float x) {
    unsigned u = __float_as_uint(x);
    return (unsigned short)((u + 0x7fffu + ((u >> 16) & 1u)) >> 16);
}
__device__ __forceinline__ float bf2f(unsigned short s) {
    return __uint_as_float(((unsigned)s) << 16);
}

// ---------------- prep_all: Uab, W_ihT, W_hhT, wx, qb in ONE launch ----------------
// blocks 0..255   : Uab row (bf16, zero-padded [256][224])
// blocks 256..455 : W_ihT[k][j] = W_ih[j][1+k]   (coalesced j writes)
// blocks 456..655 : W_hhT[k][j] = W_hh[j][k]
// block  656      : wx[j] = W_ih[j][0]
// blocks 657..784 : qb[b][h] = h0[b] @ Wa.T + ba + bua
__global__ __launch_bounds__(256) void prep_all(const float* __restrict__ Ua,
                                                const float* __restrict__ Wa,
                                                const float* __restrict__ ba,
                                                const float* __restrict__ bua,
                                                const float* __restrict__ h0,
                                                const float* __restrict__ W_ih,
                                                const float* __restrict__ W_hh,
                                                unsigned short* __restrict__ Uab,
                                                float* __restrict__ WihT,
                                                float* __restrict__ WhhT,
                                                float* __restrict__ wx,
                                                float* __restrict__ qb) {
    __shared__ float qs[H];
    int bx = blockIdx.x, tid = threadIdx.x;
    if (bx < 256) {
        if (tid < KP) {
            float v = (bx < H && tid < H) ? Ua[bx * H + tid] : 0.f;
            Uab[bx * KP + tid] = f2bf(v);
        }
    } else if (bx < 456) {
        int k = bx - 256;
        for (int j = tid; j < G4; j += 256) WihT[k * G4 + j] = W_ih[(size_t)j * (H + 1) + 1 + k];
    } else if (bx < 656) {
        int k = bx - 456;
        for (int j = tid; j < G4; j += 256) WhhT[k * G4 + j] = W_hh[(size_t)j * H + k];
    } else if (bx == 656) {
        for (int j = tid; j < G4; j += 256) wx[j] = W_ih[(size_t)j * (H + 1)];
    } else {
        int b = bx - 657;
        if (tid < H) qs[tid] = h0[b * H + tid];
        __syncthreads();
        if (tid < H) {
            float a = ba[tid] + bua[tid];
            const float* w = Wa + tid * H;
            #pragma unroll 4
            for (int k = 0; k < H; k++) a = fmaf(qs[k], w[k], a);
            qb[b * H + tid] = a;
        }
    }
}

// ---------------- fused scores + softmax(bounded) + context partials ----------------
// Grid: 2048 blocks = (b, 1/16th of T). Block: 2 chunks of 64 t.
// Wave w owns m-tiles w*4..w*4+3 (h_out 64w..64w+63), A-frags register-resident.
__global__ __launch_bounds__(256) void scores_ctx(const float* __restrict__ enc,
                                                  const unsigned short* __restrict__ Uab,
                                                  const float* __restrict__ qb,
                                                  const float* __restrict__ Va,
                                                  const float* __restrict__ bva,
                                                  float* __restrict__ ctx_raw,
                                                  float* __restrict__ lsum) {
    __shared__ unsigned short elds[64 * LROW];   // 28672 B
    __shared__ float part[4][64];
    __shared__ float s_qb[MP];
    __shared__ float s_va[MP];
    __shared__ float wlds[64];
    __shared__ float s_bound;

    int bx    = blockIdx.x;
    int b     = bx >> 4;
    int tbase = (bx & 15) * 128;
    int tid   = threadIdx.x;
    int w     = tid >> 6;
    int lane  = tid & 63;
    int r     = lane & 15;
    int q     = lane >> 4;

    // zero elds once (k-pad cols 200..223 stay 0 forever)
    for (int i = tid; i < 64 * LROW / 2; i += 256) ((unsigned*)elds)[i] = 0u;
    if (tid < MP) {
        s_qb[tid] = (tid < H) ? qb[b * H + tid] : 0.f;
        s_va[tid] = (tid < H) ? Va[tid] : 0.f;
    }
    float bv = bva[0];
    __syncthreads();

    // score upper bound: sum |Va| + |bva|  (wave 0)
    if (tid < 64) {
        float a = fabsf(s_va[tid]) + fabsf(s_va[tid + 64]) +
                  fabsf(s_va[tid + 128]) + fabsf(s_va[tid + 192]);
        #pragma unroll
        for (int d = 1; d < 64; d <<= 1) a += __shfl_xor(a, d);
        if (tid == 0) s_bound = a + fabsf(bv);
    }

    // A fragments, register-resident for the whole block
    short8 af[4][7];
    #pragma unroll
    for (int mi = 0; mi < 4; mi++)
        #pragma unroll
        for (int ks = 0; ks < 7; ks++) {
            const unsigned short* p = Uab + ((w * 4 + mi) * 16 + r) * KP + ks * 32 + q * 8;
            af[mi][ks] = *(const short8*)p;
        }

    float ctxacc = 0.f;   // per-thread (h = tid < 200) context partial
    float lacc   = 0.f;   // lane 0 of wave 0: exp-sum partial

    for (int ch = 0; ch < 2; ch++) {
        int t0 = tbase + ch * 64;
        // stage enc[b, t0..t0+63, :] -> bf16 LDS  (writers; elds consumed-barrier below)
        const float4* src = (const float4*)(enc + (size_t)(b * T + t0) * H);
        for (int i = tid; i < 64 * 50; i += 256) {
            int rr = i / 50, cc = i - rr * 50;
            float4 v = src[rr * 50 + cc];
            unsigned lo = (unsigned)f2bf(v.x) | ((unsigned)f2bf(v.y) << 16);
            unsigned hi = (unsigned)f2bf(v.z) | ((unsigned)f2bf(v.w) << 16);
            unsigned* dst = (unsigned*)(elds + rr * LROW + cc * 4);
            dst[0] = lo;
            dst[1] = hi;
        }
        __syncthreads();

        #pragma unroll
        for (int nt = 0; nt < 4; nt++) {
            floatx4 Cm[4];
            #pragma unroll
            for (int mi = 0; mi < 4; mi++) Cm[mi] = (floatx4){0.f, 0.f, 0.f, 0.f};
            #pragma unroll
            for (int ks = 0; ks < 7; ks++) {
                short8 bf = *(const short8*)(elds + (nt * 16 + r) * LROW + ks * 32 + q * 8);
                #pragma unroll
                for (int mi = 0; mi < 4; mi++)
                    Cm[mi] = __builtin_amdgcn_mfma_f32_16x16x32_bf16(af[mi][ks], bf, Cm[mi], 0, 0, 0);
            }
            float p = 0.f;
            #pragma unroll
            for (int mi = 0; mi < 4; mi++)
                #pragma unroll
                for (int rg = 0; rg < 4; rg++) {
                    int h = (w * 4 + mi) * 16 + q * 4 + rg;
                    p += s_va[h] * tanhf(s_qb[h] + Cm[mi][rg]);
                }
            p += __shfl_xor(p, 16);
            p += __shfl_xor(p, 32);
            if (q == 0) part[w][nt * 16 + r] = p;
        }
        __syncthreads();

        if (tid < 64) {   // wave 0: score -> bounded-softmax weight
            float s  = part[0][tid] + part[1][tid] + part[2][tid] + part[3][tid] + bv;
            float we = expf(s - s_bound);
            wlds[tid] = we;
            float wv = we;
            #pragma unroll
            for (int d = 1; d < 64; d <<= 1) wv += __shfl_xor(wv, d);
            if (tid == 0) lacc += wv;
        }
        __syncthreads();

        // context partial from LDS-resident tile: ctx[h] += sum_t w[t]*enc[t,h]
        if (tid < H) {
            float a = ctxacc;
            #pragma unroll 4
            for (int t = 0; t < 64; t++)
                a = fmaf(wlds[t], bf2f(elds[t * LROW + tid]), a);
            ctxacc = a;
        }
        __syncthreads();   // elds consumed before next chunk's staging
    }

    if (tid < H)  atomicAdd(&ctx_raw[b * H + tid], ctxacc);
    if (tid == 0) atomicAdd(&lsum[b], lacc);
}

// ---------------- decoder: hpre inline, 5 steps, one block per batch ----------------
__device__ __forceinline__ float sigm(float x) { return 1.f / (1.f + expf(-x)); }

__global__ __launch_bounds__(256) void decoder_kernel(const float* __restrict__ x,
                                                      const float* __restrict__ h0,
                                                      const float* __restrict__ c0,
                                                      const float* __restrict__ ctx_raw,
                                                      const float* __restrict__ lsum,
                                                      const float* __restrict__ WihT,
                                                      const float* __restrict__ wx,
                                                      const float* __restrict__ b_ih,
                                                      const float* __restrict__ WhhT,
                                                      const float* __restrict__ b_hh,
                                                      const float* __restrict__ W1,
                                                      const float* __restrict__ b1,
                                                      const float* __restrict__ W2,
                                                      const float* __restrict__ b2,
                                                      const float* __restrict__ W3,
                                                      const float* __restrict__ b3,
                                                      float* __restrict__ out) {
    int b = blockIdx.x, tid = threadIdx.x;
    __shared__ float s_ctx[H];
    __shared__ float s_q[H];
    __shared__ float s_gc[G4];
    __shared__ float s_wx[G4];
    __shared__ float s_out[H];
    __shared__ float s_o1[100];
    __shared__ float s_o2[50];
    __shared__ float s_x;

    float cprev = 0.f;
    if (tid < H) {
        float invl = 1.f / lsum[b];
        s_ctx[tid] = ctx_raw[b * H + tid] * invl;
        s_q[tid]   = h0[b * H + tid];
        cprev      = c0[b * H + tid];
    }
    if (tid == 0) s_x = x[b];
    __syncthreads();

    // g_const[j] = b_ih[j] + b_hh[j] + ctx.W_ih[j,1:] + q.W_hh[j,:]  (coalesced via transposes)
    #pragma unroll
    for (int p = 0; p < 4; p++) {
        int j = tid + p * 256;
        if (j < G4) {
            float a = b_ih[j] + b_hh[j];
            #pragma unroll 2
            for (int k = 0; k < H; k++)
                a = fmaf(s_ctx[k], WihT[k * G4 + j], fmaf(s_q[k], WhhT[k * G4 + j], a));
            s_gc[j] = a;
            s_wx[j] = wx[j];
        }
    }
    __syncthreads();

    for (int s = 0; s < 5; s++) {
        float xv = s_x;
        __syncthreads();
        if (tid < H) {
            float ig = s_gc[tid]         + xv * s_wx[tid];
            float fg = s_gc[H + tid]     + xv * s_wx[H + tid];
            float gg = s_gc[2 * H + tid] + xv * s_wx[2 * H + tid];
            float og = s_gc[3 * H + tid] + xv * s_wx[3 * H + tid];
            float c  = sigm(fg) * cprev + sigm(ig) * tanhf(gg);
            float hn = sigm(og) * tanhf(c);
            s_out[tid] = fmaxf(hn, 0.f);
        }
        __syncthreads();
        if (tid < 100) {
            float a = b1[tid];
            #pragma unroll 4
            for (int k = 0; k < H; k++) a = fmaf(W1[tid * H + k], s_out[k], a);
            s_o1[tid] = fmaxf(a, 0.f);
        }
        __syncthreads();
        if (tid < 50) {
            float a = b2[tid];
            #pragma unroll 4
            for (int k = 0; k < 100; k++) a = fmaf(W2[tid * 100 + k], s_o1[k], a);
            s_o2[tid] = fmaxf(a, 0.f);
        }
        __syncthreads();
        if (tid == 0) {
            float a = b3[0];
            for (int k = 0; k < 50; k++) a = fmaf(W3[k], s_o2[k], a);
            out[b * 5 + s] = a;
            s_x = a;
        }
        __syncthreads();
    }
}

// ---------------- launch ----------------
extern "C" void kernel_launch(void* const* d_in, const int* in_sizes, int n_in,
                              void* d_out, int out_size, void* d_ws, size_t ws_size,
                              hipStream_t stream) {
    (void)in_sizes; (void)n_in; (void)out_size; (void)ws_size;
    const float* x    = (const float*)d_in[0];
    const float* h0   = (const float*)d_in[1];
    const float* c0   = (const float*)d_in[2];
    const float* enc  = (const float*)d_in[3];
    const float* Wa   = (const float*)d_in[4];
    const float* ba   = (const float*)d_in[5];
    const float* Ua   = (const float*)d_in[6];
    const float* bua  = (const float*)d_in[7];
    const float* Va   = (const float*)d_in[8];
    const float* bva  = (const float*)d_in[9];
    const float* W_ih = (const float*)d_in[10];
    const float* W_hh = (const float*)d_in[11];
    const float* b_ih = (const float*)d_in[12];
    const float* b_hh = (const float*)d_in[13];
    const float* W1   = (const float*)d_in[14];
    const float* b1   = (const float*)d_in[15];
    const float* W2   = (const float*)d_in[16];
    const float* b2   = (const float*)d_in[17];
    const float* W3   = (const float*)d_in[18];
    const float* b3   = (const float*)d_in[19];
    float* out = (float*)d_out;

    char* ws = (char*)d_ws;
    unsigned short* Uab = (unsigned short*)(ws);   // 114688
    float* WihT    = (float*)(ws + 114688);        // 640000
    float* WhhT    = (float*)(ws + 754688);        // 640000
    float* wx      = (float*)(ws + 1394688);       // 3200
    float* qb      = (float*)(ws + 1397888);       // 102400
    float* ctx_raw = (float*)(ws + 1500288);       // 102400
    float* lsum    = (float*)(ws + 1602688);       // 512   (total ~1.6 MB)

    hipMemsetAsync(ws + 1500288, 0, 102912, stream);   // ctx_raw + lsum
    prep_all<<<dim3(785), 256, 0, stream>>>(Ua, Wa, ba, bua, h0, W_ih, W_hh,
                                            Uab, WihT, WhhT, wx, qb);
    scores_ctx<<<dim3(2048), 256, 0, stream>>>(enc, Uab, qb, Va, bva, ctx_raw, lsum);
    decoder_kernel<<<dim3(B), 256, 0, stream>>>(x, h0, c0, ctx_raw, lsum,
                                                WihT, wx, b_ih, WhhT, b_hh,
                                                W1, b1, W2, b2, W3, b3, out);
}

// Round 4
// 479.511 us; speedup vs baseline: 1.8218x; 1.2618x over previous
//
#include <hip/hip_runtime.h>
#include <math.h>

#define B 128
#define T 2048
#define H 200
#define G4 800   // 4*H
#define KP 224   // K padded to multiple of 32
#define LROW 224 // LDS row stride (bf16 units) for enc tile

typedef short short8 __attribute__((ext_vector_type(8)));
typedef float floatx4 __attribute__((ext_vector_type(4)));

__device__ __forceinline__ unsigned short f2bf(float x) {
    unsigned u = __float_as_uint(x);
    return (unsigned short)((u + 0x7fffu + ((u >> 16) & 1u)) >> 16);
}
__device__ __forceinline__ float bf2f(unsigned short s) {
    return __uint_as_float(((unsigned)s) << 16);
}
// pack two floats -> two bf16 (round-nearest-away) in 3 VALU ops
__device__ __forceinline__ unsigned pk2(float a, float b) {
    return __builtin_amdgcn_perm(__float_as_uint(b) + 0x8000u,
                                 __float_as_uint(a) + 0x8000u, 0x07060302u);
}
// tanh(x) = 1 - 2/(exp(2x)+1), hw exp2 + rcp (~1e-6 rel err)
__device__ __forceinline__ float ftanh(float x) {
    float e = __builtin_amdgcn_exp2f(x * 2.885390081777927f);
    float r = __builtin_amdgcn_rcpf(e + 1.f);
    return fmaf(-2.f, r, 1.f);
}
__device__ __forceinline__ float sigm(float x) { return 1.f / (1.f + expf(-x)); }

// ---------------- prep_all ----------------
// blocks 0..255    : Uab row (bf16, zero-padded [256][224])
// blocks 256..455  : W_ihT[k][j] = W_ih[j][1+k]
// blocks 456..655  : W_hhT[k][j] = W_hh[j][k]
// block  656       : wx[j] = W_ih[j][0]
// blocks 657..784  : qb[b][h] = h0[b] @ Wa.T + ba + bua
// blocks 785..984  : W1T[k][j] = W1[j][k]   (k<200, j<100)
// blocks 985..1084 : W2T[k][j] = W2[j][k]   (k<100, j<50)
__global__ __launch_bounds__(256) void prep_all(const float* __restrict__ Ua,
                                                const float* __restrict__ Wa,
                                                const float* __restrict__ ba,
                                                const float* __restrict__ bua,
                                                const float* __restrict__ h0,
                                                const float* __restrict__ W_ih,
                                                const float* __restrict__ W_hh,
                                                const float* __restrict__ W1,
                                                const float* __restrict__ W2,
                                                unsigned short* __restrict__ Uab,
                                                float* __restrict__ WihT,
                                                float* __restrict__ WhhT,
                                                float* __restrict__ wx,
                                                float* __restrict__ qb,
                                                float* __restrict__ W1T,
                                                float* __restrict__ W2T) {
    __shared__ float qs[H];
    int bx = blockIdx.x, tid = threadIdx.x;
    if (bx < 256) {
        if (tid < KP) {
            float v = (bx < H && tid < H) ? Ua[bx * H + tid] : 0.f;
            Uab[bx * KP + tid] = f2bf(v);
        }
    } else if (bx < 456) {
        int k = bx - 256;
        for (int j = tid; j < G4; j += 256) WihT[k * G4 + j] = W_ih[(size_t)j * (H + 1) + 1 + k];
    } else if (bx < 656) {
        int k = bx - 456;
        for (int j = tid; j < G4; j += 256) WhhT[k * G4 + j] = W_hh[(size_t)j * H + k];
    } else if (bx == 656) {
        for (int j = tid; j < G4; j += 256) wx[j] = W_ih[(size_t)j * (H + 1)];
    } else if (bx < 785) {
        int b = bx - 657;
        if (tid < H) qs[tid] = h0[b * H + tid];
        __syncthreads();
        if (tid < H) {
            float a = ba[tid] + bua[tid];
            const float* w = Wa + tid * H;
            #pragma unroll 4
            for (int k = 0; k < H; k++) a = fmaf(qs[k], w[k], a);
            qb[b * H + tid] = a;
        }
    } else if (bx < 985) {
        int k = bx - 785;
        if (tid < 100) W1T[k * 100 + tid] = W1[tid * H + k];
    } else {
        int k = bx - 985;
        if (tid < 50) W2T[k * 50 + tid] = W2[tid * 100 + k];
    }
}

// ---------------- fused scores + bounded-softmax + context partials ----------------
// Grid: 4096 blocks = (b, 1/32 of T): one 64-t chunk per block.
// Wave w owns m-tiles 4w..4w+3 processed in 2 groups of 2 (A-frags reloaded from
// L2-hot Uab per group -> peak regs ~100, 4 waves/SIMD).
__global__ __launch_bounds__(256, 4) void scores_ctx(const float* __restrict__ enc,
                                                     const unsigned short* __restrict__ Uab,
                                                     const float* __restrict__ qb,
                                                     const float* __restrict__ Va,
                                                     const float* __restrict__ bva,
                                                     float* __restrict__ ctx_raw,
                                                     float* __restrict__ lsum) {
    __shared__ unsigned short elds[64 * LROW];   // 28672 B
    __shared__ float part[4][64];
    __shared__ float s_qb[256];
    __shared__ float s_va[256];
    __shared__ float wlds[64];
    __shared__ float s_bound;

    int bx   = blockIdx.x;
    int b    = bx >> 5;
    int t0   = (bx & 31) * 64;
    int tid  = threadIdx.x;
    int w    = tid >> 6;
    int lane = tid & 63;
    int r    = lane & 15;
    int q    = lane >> 4;

    // zero k-pad columns 200..223 (12 uints per row)
    for (int i = tid; i < 64 * 12; i += 256) {
        int rr = i / 12, cc = i - rr * 12;
        *(unsigned*)(elds + rr * LROW + 200 + 2 * cc) = 0u;
    }
    s_qb[tid] = (tid < H) ? qb[b * H + tid] : 0.f;
    s_va[tid] = (tid < H) ? Va[tid] : 0.f;
    float bv = bva[0];

    // stage enc[b, t0..t0+63, :] -> bf16 LDS (coalesced dwordx4, 3 VALU per pair)
    const float4* src = (const float4*)(enc + (size_t)(b * T + t0) * H);
    for (int i = tid; i < 64 * 50; i += 256) {
        int rr = i / 50, cc = i - rr * 50;
        float4 v = src[i];
        unsigned* dst = (unsigned*)(elds + rr * LROW + cc * 4);
        dst[0] = pk2(v.x, v.y);
        dst[1] = pk2(v.z, v.w);
    }
    __syncthreads();

    // score bound = sum|Va| + |bva|  (wave 0; s_va complete after barrier)
    if (tid < 64) {
        float a = fabsf(s_va[tid]) + fabsf(s_va[tid + 64]) +
                  fabsf(s_va[tid + 128]) + fabsf(s_va[tid + 192]);
        #pragma unroll
        for (int d = 1; d < 64; d <<= 1) a += __shfl_xor(a, d);
        if (tid == 0) s_bound = a + fabsf(bv);
    }

    float p[4] = {0.f, 0.f, 0.f, 0.f};   // per-lane score partials, t = nt*16+r

    for (int mig = 0; mig < 2; ++mig) {
        int m0 = w * 4 + mig * 2;
        short8 af[2][7];
        #pragma unroll
        for (int mi = 0; mi < 2; mi++)
            #pragma unroll
            for (int ks = 0; ks < 7; ks++)
                af[mi][ks] = *(const short8*)(Uab + ((m0 + mi) * 16 + r) * KP + ks * 32 + q * 8);

        #pragma unroll
        for (int nt = 0; nt < 4; nt++) {
            floatx4 C0 = (floatx4){0.f, 0.f, 0.f, 0.f};
            floatx4 C1 = (floatx4){0.f, 0.f, 0.f, 0.f};
            #pragma unroll
            for (int ks = 0; ks < 7; ks++) {
                short8 bf = *(const short8*)(elds + (nt * 16 + r) * LROW + ks * 32 + q * 8);
                C0 = __builtin_amdgcn_mfma_f32_16x16x32_bf16(af[0][ks], bf, C0, 0, 0, 0);
                C1 = __builtin_amdgcn_mfma_f32_16x16x32_bf16(af[1][ks], bf, C1, 0, 0, 0);
            }
            float pp = 0.f;
            #pragma unroll
            for (int rg = 0; rg < 4; rg++) {
                int h0i = m0 * 16 + q * 4 + rg;
                int h1i = h0i + 16;
                pp += s_va[h0i] * ftanh(s_qb[h0i] + C0[rg]);
                pp += s_va[h1i] * ftanh(s_qb[h1i] + C1[rg]);
            }
            p[nt] += pp;
        }
    }
    #pragma unroll
    for (int nt = 0; nt < 4; nt++) {
        float pp = p[nt];
        pp += __shfl_xor(pp, 16);
        pp += __shfl_xor(pp, 32);
        if (q == 0) part[w][nt * 16 + r] = pp;
    }
    __syncthreads();

    float lacc = 0.f;
    if (tid < 64) {   // wave 0: score -> bounded-softmax weight
        float s  = part[0][tid] + part[1][tid] + part[2][tid] + part[3][tid] + bv;
        float we = expf(s - s_bound);
        wlds[tid] = we;
        #pragma unroll
        for (int d = 1; d < 64; d <<= 1) we += __shfl_xor(we, d);
        lacc = we;
    }
    __syncthreads();

    if (tid < H) {   // ctx[h] += sum_t w[t]*enc[t,h] from LDS-resident tile
        float a = 0.f;
        #pragma unroll 4
        for (int t = 0; t < 64; t++)
            a = fmaf(wlds[t], bf2f(elds[t * LROW + tid]), a);
        atomicAdd(&ctx_raw[b * H + tid], a);
    }
    if (tid == 0) atomicAdd(&lsum[b], lacc);
}

// ---------------- gates_const: gc[b][j] = b_ih+b_hh + ctx.Wih[:,1:] + q.Whh ----------------
// Grid: 512 = (b, quarter). Coalesced via transposed weights.
__global__ __launch_bounds__(256) void gates_const(const float* __restrict__ ctx_raw,
                                                   const float* __restrict__ lsum,
                                                   const float* __restrict__ h0,
                                                   const float* __restrict__ WihT,
                                                   const float* __restrict__ WhhT,
                                                   const float* __restrict__ b_ih,
                                                   const float* __restrict__ b_hh,
                                                   float* __restrict__ gc) {
    int b = blockIdx.x >> 2, quarter = blockIdx.x & 3;
    int tid = threadIdx.x;
    __shared__ float s_ctx[H];
    __shared__ float s_q[H];
    if (tid < H) {
        float invl = 1.f / lsum[b];
        s_ctx[tid] = ctx_raw[b * H + tid] * invl;
        s_q[tid]   = h0[b * H + tid];
    }
    __syncthreads();
    if (tid < H) {
        int j = quarter * H + tid;
        float a = b_ih[j] + b_hh[j];
        #pragma unroll 2
        for (int k = 0; k < H; k++) {
            a = fmaf(s_ctx[k], WihT[k * G4 + j], a);
            a = fmaf(s_q[k],   WhhT[k * G4 + j], a);
        }
        gc[b * G4 + j] = a;
    }
}

// ---------------- decoder: 5 steps, one block per batch ----------------
__global__ __launch_bounds__(256) void decoder_kernel(const float* __restrict__ x,
                                                      const float* __restrict__ c0,
                                                      const float* __restrict__ gc,
                                                      const float* __restrict__ wx,
                                                      const float* __restrict__ W1T,
                                                      const float* __restrict__ b1,
                                                      const float* __restrict__ W2T,
                                                      const float* __restrict__ b2,
                                                      const float* __restrict__ W3,
                                                      const float* __restrict__ b3,
                                                      float* __restrict__ out) {
    int b = blockIdx.x, tid = threadIdx.x;
    __shared__ float s_gc[G4];
    __shared__ float s_wx[G4];
    __shared__ float s_out[H];
    __shared__ float s_o1[100];
    __shared__ float s_o2[50];
    __shared__ float s_x;

    float cprev = (tid < H) ? c0[b * H + tid] : 0.f;
    #pragma unroll
    for (int pp = 0; pp < 4; pp++) {
        int j = tid + pp * 256;
        if (j < G4) {
            s_gc[j] = gc[b * G4 + j];
            s_wx[j] = wx[j];
        }
    }
    if (tid == 0) s_x = x[b];
    __syncthreads();

    for (int s = 0; s < 5; s++) {
        float xv = s_x;
        __syncthreads();
        if (tid < H) {
            float ig = s_gc[tid]         + xv * s_wx[tid];
            float fg = s_gc[H + tid]     + xv * s_wx[H + tid];
            float gg = s_gc[2 * H + tid] + xv * s_wx[2 * H + tid];
            float og = s_gc[3 * H + tid] + xv * s_wx[3 * H + tid];
            float c  = sigm(fg) * cprev + sigm(ig) * tanhf(gg);
            float hn = sigm(og) * tanhf(c);
            s_out[tid] = fmaxf(hn, 0.f);
        }
        __syncthreads();
        if (tid < 100) {
            float a = b1[tid];
            #pragma unroll 4
            for (int k = 0; k < H; k++) a = fmaf(W1T[k * 100 + tid], s_out[k], a);
            s_o1[tid] = fmaxf(a, 0.f);
        }
        __syncthreads();
        if (tid < 50) {
            float a = b2[tid];
            #pragma unroll 4
            for (int k = 0; k < 100; k++) a = fmaf(W2T[k * 50 + tid], s_o1[k], a);
            s_o2[tid] = fmaxf(a, 0.f);
        }
        __syncthreads();
        if (tid == 0) {
            float a = b3[0];
            for (int k = 0; k < 50; k++) a = fmaf(W3[k], s_o2[k], a);
            out[b * 5 + s] = a;
            s_x = a;
        }
        __syncthreads();
    }
}

// ---------------- launch ----------------
extern "C" void kernel_launch(void* const* d_in, const int* in_sizes, int n_in,
                              void* d_out, int out_size, void* d_ws, size_t ws_size,
                              hipStream_t stream) {
    (void)in_sizes; (void)n_in; (void)out_size; (void)ws_size;
    const float* x    = (const float*)d_in[0];
    const float* h0   = (const float*)d_in[1];
    const float* c0   = (const float*)d_in[2];
    const float* enc  = (const float*)d_in[3];
    const float* Wa   = (const float*)d_in[4];
    const float* ba   = (const float*)d_in[5];
    const float* Ua   = (const float*)d_in[6];
    const float* bua  = (const float*)d_in[7];
    const float* Va   = (const float*)d_in[8];
    const float* bva  = (const float*)d_in[9];
    const float* W_ih = (const float*)d_in[10];
    const float* W_hh = (const float*)d_in[11];
    const float* b_ih = (const float*)d_in[12];
    const float* b_hh = (const float*)d_in[13];
    const float* W1   = (const float*)d_in[14];
    const float* b1   = (const float*)d_in[15];
    const float* W2   = (const float*)d_in[16];
    const float* b2   = (const float*)d_in[17];
    const float* W3   = (const float*)d_in[18];
    const float* b3   = (const float*)d_in[19];
    float* out = (float*)d_out;

    char* ws = (char*)d_ws;
    unsigned short* Uab = (unsigned short*)(ws);   // 114688
    float* WihT    = (float*)(ws + 114688);        // 640000
    float* WhhT    = (float*)(ws + 754688);        // 640000
    float* wx      = (float*)(ws + 1394688);       // 3200
    float* qb      = (float*)(ws + 1397888);       // 102400
    float* W1T     = (float*)(ws + 1500288);       // 80000
    float* W2T     = (float*)(ws + 1580288);       // 20000
    float* ctx_raw = (float*)(ws + 1600288);       // 102400
    float* lsum    = (float*)(ws + 1702688);       // 512
    float* gc      = (float*)(ws + 1703200);       // 409600 (total ~2.11 MB)

    hipMemsetAsync(ws + 1600288, 0, 102912, stream);   // ctx_raw + lsum
    prep_all<<<dim3(1085), 256, 0, stream>>>(Ua, Wa, ba, bua, h0, W_ih, W_hh, W1, W2,
                                             Uab, WihT, WhhT, wx, qb, W1T, W2T);
    scores_ctx<<<dim3(4096), 256, 0, stream>>>(enc, Uab, qb, Va, bva, ctx_raw, lsum);
    gates_const<<<dim3(512), 256, 0, stream>>>(ctx_raw, lsum, h0, WihT, WhhT, b_ih, b_hh, gc);
    decoder_kernel<<<dim3(B), 256, 0, stream>>>(x, c0, gc, wx, W1T, b1, W2T, b2, W3, b3, out);
}